// Round 6
// baseline (347.777 us; speedup 1.0000x reference)
//
#include <hip/hip_runtime.h>
#include <stdint.h>

typedef unsigned short u16;
typedef __bf16 bf16x8 __attribute__((ext_vector_type(8)));
typedef float f32x4 __attribute__((ext_vector_type(4)));

__device__ __forceinline__ u16 f2bf(float f) {
  union { float f; uint32_t u; } x; x.f = f;
  uint32_t u = x.u;
  u += 0x7fffu + ((u >> 16) & 1u);   // round-to-nearest-even
  return (u16)(u >> 16);
}
__device__ __forceinline__ float bf2f(uint32_t lo16) {
  union { uint32_t u; float f; } x; x.u = lo16 << 16; return x.f;
}
__device__ __forceinline__ float bfhi(uint32_t u) {
  union { uint32_t u; float f; } x; x.u = u & 0xffff0000u; return x.f;
}
// fix one bf16 pair: e_k = m_k + p_k * F_k, repacked to bf16x2
__device__ __forceinline__ uint32_t fixpair(uint32_t m, float p0, float p1,
                                            float F0, float F1) {
  float e0 = fmaf(p0, F0, bf2f(m & 0xffffu));
  float e1 = fmaf(p1, F1, bfhi(m));
  return (uint32_t)f2bf(e0) | ((uint32_t)f2bf(e1) << 16);
}

__device__ __forceinline__ void async_load16(const u16* g, u16* l) {
  __builtin_amdgcn_global_load_lds(
      (const __attribute__((address_space(1))) void*)g,
      (__attribute__((address_space(3))) void*)l,
      16, 0, 0);
}

// ---------------- prep_all: sigmoid(beta)+bpow table + weight/x converts ----------------
// bpow[p][h] = beta_h^p for p = 1..32 (fp32, 132 KB, L2-resident); bpow[32] is
// also ffold's beta^32 ratio.
__global__ __launch_bounds__(256) void prep_all(const float* __restrict__ x,
                                                const float* __restrict__ Wq,
                                                const float* __restrict__ Wfc,
                                                const float* __restrict__ braw,
                                                u16* __restrict__ xb,
                                                u16* __restrict__ wqb,
                                                u16* __restrict__ wfcb,
                                                float* __restrict__ beta,
                                                float* __restrict__ bpow) {
  int gid = blockIdx.x * 256 + threadIdx.x;
  if (gid < 1024) {
    float b = 1.0f / (1.0f + expf(-braw[gid]));
    beta[gid] = b;
    float w = b;
#pragma unroll 1
    for (int p = 1; p <= 32; p++) { bpow[p * 1024 + gid] = w; w *= b; }
  }
  if (gid < 131072) {
    const int HH = 1024 * 1024;
    int i = gid * 16;
    const float* src = (i < HH) ? (Wq + i) : (Wfc + (i - HH));
    u16* dst = (i < HH) ? (wqb + i) : (wfcb + (i - HH));
#pragma unroll
    for (int c = 0; c < 4; c++) {
      float4 v = *(const float4*)(src + c * 4);
      ushort4 o = {f2bf(v.x), f2bf(v.y), f2bf(v.z), f2bf(v.w)};
      *(ushort4*)(dst + c * 4) = o;
    }
  }
  {
    int i = gid * 8;
    float4 a = *(const float4*)(x + i);
    float4 b = *(const float4*)(x + i + 4);
    ushort4 o0 = {f2bf(a.x), f2bf(a.y), f2bf(a.z), f2bf(a.w)};
    ushort4 o1 = {f2bf(b.x), f2bf(b.y), f2bf(b.z), f2bf(b.w)};
    *(ushort4*)(xb + i) = o0;
    *(ushort4*)(xb + i + 4) = o1;
  }
}

// ---------------- GEMM1 + fused segment-local scan: m_local = localscan(x Wq^T + b) ----
// Ring schedule = R1/R4 harness-verified (256x256 tile, BK=32, 4-deep LDS ring,
// counted vmcnt(8), XCD swizzle). Epilogue computes the FULL segment-local scan
// in-register (one block = one 32t x 8b segment) and writes bf16 m_local + the
// segment carry m(31). fp32 q feeds the scan (better than bf16-q rescan).
//
// Lane algebra (C/D layout col=lane&15, row=(lane>>4)*4+r, m89/m91):
//   row = wr + 16 i + 4 c4 + r  (c4 = lane>>4)  ->  b = (4 c4 + r) & 7,
//   t = 16 W + 2 i + kap   (W = wr>>7, kap = c4>>1).
// Parity scan: S_i = per-lane beta^2-prefix; partner (lane^32: same b,h, other
// parity) exchanged via shfl_xor; m_i = S_i + beta * (kap ? R_i : R_{i-1}).
// t-half combine: W0/kap1 lanes export m(15) to sm15[8][256] (8 KB in ring
// slot 0 -- last ds_read at kt=28, whose end barrier is collective; slots 1-3
// read by lagging waves are disjoint); after __syncthreads, W1 adds
// beta^{2i+kap+1} * m15. carry[seg][b][h] = final acc[7] of W1/kap1 lanes.
__global__ __launch_bounds__(512, 2) void gemm_scan(const u16* __restrict__ A,
                                                    const u16* __restrict__ B,
                                                    const float* __restrict__ bias,
                                                    u16* __restrict__ Cout,
                                                    const float* __restrict__ beta_arr,
                                                    float* __restrict__ carry_out,
                                                    int M, int N, int K) {
  __shared__ u16 lds[4][2][256 * 32];  // 128 KiB ring

  const int tid  = threadIdx.x;
  const int lane = tid & 63;
  const int wid  = tid >> 6;
  const int wr   = (wid >> 2) * 128;
  const int wc   = (wid & 3) * 64;

  const int bid    = blockIdx.x;
  const int xcd    = bid & 7;
  const int idx    = bid >> 3;
  const int tile_m = ((xcd << 3) | (idx >> 2)) * 256;
  const int tile_n = (idx & 3) * 256;

  const int srow    = tid >> 2;
  const int schunk  = (tid & 3) ^ ((srow >> 1) & 3);
  const u16* gA = A + (size_t)(tile_m + srow) * K + schunk * 8;
  const u16* gB = B + (size_t)(tile_n + srow) * K + schunk * 8;
  const size_t half_stride = (size_t)128 * K;

#define STAGE(slot, kt)                                                   \
  do {                                                                    \
    const size_t k0 = (size_t)(kt) * 32;                                  \
    async_load16(gA + k0,               &lds[slot][0][wid * 512]);        \
    async_load16(gA + k0 + half_stride, &lds[slot][0][4096 + wid * 512]); \
    async_load16(gB + k0,               &lds[slot][1][wid * 512]);        \
    async_load16(gB + k0 + half_stride, &lds[slot][1][4096 + wid * 512]); \
  } while (0)

  f32x4 acc[8][4];
#pragma unroll
  for (int i = 0; i < 8; i++)
#pragma unroll
    for (int j = 0; j < 4; j++) acc[i][j] = (f32x4){0.f, 0.f, 0.f, 0.f};

  const int lrow = lane & 15;
  const int kq   = lane >> 4;
  const int kc   = (lrow >> 1) & 3;
  const int coff = ((kq ^ kc) << 3);

  const int NKT = K >> 5;  // 32

  STAGE(0, 0);
  if (NKT > 1) STAGE(1, 1);
  if (NKT > 2) STAGE(2, 2);
  if (NKT > 2)      asm volatile("s_waitcnt vmcnt(8)" ::: "memory");
  else if (NKT > 1) asm volatile("s_waitcnt vmcnt(4)" ::: "memory");
  else              asm volatile("s_waitcnt vmcnt(0)" ::: "memory");
  __builtin_amdgcn_s_barrier();

  for (int kt = 0; kt < NKT; ++kt) {
    const int slot = kt & 3;
    const u16* As = &lds[slot][0][0];
    const u16* Bs = &lds[slot][1][0];

    bf16x8 a[8], b[4];
#pragma unroll
    for (int i = 0; i < 8; i++)
      a[i] = *(const bf16x8*)&As[(wr + i * 16 + lrow) * 32 + coff];
#pragma unroll
    for (int j = 0; j < 4; j++)
      b[j] = *(const bf16x8*)&Bs[(wc + j * 16 + lrow) * 32 + coff];

    if (kt + 3 < NKT) STAGE((kt + 3) & 3, kt + 3);

    __builtin_amdgcn_s_setprio(1);
#pragma unroll
    for (int i = 0; i < 8; i++)
#pragma unroll
      for (int j = 0; j < 4; j++)
        acc[i][j] = __builtin_amdgcn_mfma_f32_16x16x32_bf16(a[i], b[j], acc[i][j], 0, 0, 0);
    __builtin_amdgcn_s_setprio(0);

    const int ahead = NKT - 1 - kt;
    if (ahead >= 3) {
      asm volatile("s_waitcnt vmcnt(8)" ::: "memory");
      __builtin_amdgcn_s_barrier();
    } else if (ahead == 2) {
      asm volatile("s_waitcnt vmcnt(4)" ::: "memory");
      __builtin_amdgcn_s_barrier();
    } else if (ahead == 1) {
      asm volatile("s_waitcnt vmcnt(0)" ::: "memory");
      __builtin_amdgcn_s_barrier();
    }
  }
#undef STAGE

  // ---------------- fused segment-local scan epilogue ----------------
  const int crow = (lane >> 4) << 2;
  const int ccol = lane & 15;
  const int c4   = lane >> 4;
  const int kap  = c4 >> 1;
  const int Wh   = wr >> 7;
  float* sm15 = (float*)&lds[0][0][0];  // [8][256] fp32, 8 KB (ring slot 0)

  // Phase A: local (t-half) scan, in place in acc
#pragma unroll
  for (int j = 0; j < 4; j++) {
    const int gn = tile_n + wc + j * 16 + ccol;
    const float bv = bias[gn];
    const float be = beta_arr[gn];
    const float be2 = be * be;
#pragma unroll
    for (int r = 0; r < 4; r++) {
      float S[8], R[8];
      S[0] = acc[0][j][r] + bv;
#pragma unroll
      for (int i = 1; i < 8; i++) S[i] = fmaf(be2, S[i - 1], acc[i][j][r] + bv);
#pragma unroll
      for (int i = 0; i < 8; i++) R[i] = __shfl_xor(S[i], 32);
      acc[0][j][r] = kap ? fmaf(be, R[0], S[0]) : S[0];
#pragma unroll
      for (int i = 1; i < 8; i++)
        acc[i][j][r] = fmaf(be, kap ? R[i] : R[i - 1], S[i]);
    }
  }
  // Phase B: export m(15)
  if (Wh == 0 && kap == 1) {
#pragma unroll
    for (int j = 0; j < 4; j++)
#pragma unroll
      for (int r = 0; r < 4; r++) {
        const int bb = ((c4 << 2) + r) & 7;
        sm15[bb * 256 + wc + j * 16 + ccol] = acc[7][j][r];
      }
  }
  __syncthreads();
  // Phase C: upper half adds beta^{2i+kap+1} * m(15)
  if (Wh == 1) {
#pragma unroll
    for (int j = 0; j < 4; j++) {
      const int hl = wc + j * 16 + ccol;
      const float be = beta_arr[tile_n + hl];
      const float be2 = be * be;
#pragma unroll
      for (int r = 0; r < 4; r++) {
        const int bb = ((c4 << 2) + r) & 7;
        const float v = sm15[bb * 256 + hl];
        float f = kap ? be2 : be;
#pragma unroll
        for (int i = 0; i < 8; i++) {
          acc[i][j][r] = fmaf(f, v, acc[i][j][r]);
          f *= be2;
        }
      }
    }
  }
  // Phase D: store bf16 m_local (+ per-segment carry from registers)
#pragma unroll
  for (int i = 0; i < 8; i++) {
#pragma unroll
    for (int j = 0; j < 4; j++) {
      const int gm = tile_m + wr + i * 16 + crow;
      const int gn = tile_n + wc + j * 16 + ccol;
#pragma unroll
      for (int r = 0; r < 4; r++)
        Cout[(size_t)(gm + r) * N + gn] = f2bf(acc[i][j][r]);
    }
  }
  if (Wh == 1 && kap == 1) {
    const int seg = tile_m >> 8;
#pragma unroll
    for (int j = 0; j < 4; j++) {
      const int hl = wc + j * 16 + ccol;
#pragma unroll
      for (int r = 0; r < 4; r++) {
        const int bb = ((c4 << 2) + r) & 7;
        carry_out[(size_t)seg * 8192 + bb * 1024 + tile_n + hl] = acc[7][j][r];
      }
    }
  }
}

// ---------------- ffold: F[s] = beta^32 * F[s-1] + carry[s-1], F[0] = 0 ----------------
// 2048 threads x float4; 4 MB L2 traffic.
// R5 BUG WAS HERE: b32 must be indexed by h = (cq*4) & 1023 (the beta^32 table
// is per-h, 1024 entries), NOT cq*4 (which spans the 8192-wide (b,h) vector and
// read 28 KB past bpow into the carry buffer -> garbage ratios -> inf).
__global__ __launch_bounds__(256) void ffold(const float4* __restrict__ carry4,
                                             const float* __restrict__ bpow,
                                             float4* __restrict__ Fbuf) {
  const int cq = blockIdx.x * 256 + threadIdx.x;  // 0..2047  (= b*256 + h/4)
  const int hq = cq & 255;                        // h quad: h = hq*4 .. hq*4+3
  const float4 b32 = *(const float4*)&bpow[32 * 1024 + hq * 4];
  float4 F = make_float4(0.f, 0.f, 0.f, 0.f);
  for (int s = 0; s < 64; s++) {
    Fbuf[(size_t)s * 2048 + cq] = F;
    float4 c = carry4[(size_t)s * 2048 + cq];
    F.x = fmaf(b32.x, F.x, c.x);
    F.y = fmaf(b32.y, F.y, c.y);
    F.z = fmaf(b32.z, F.z, c.z);
    F.w = fmaf(b32.w, F.w, c.w);
  }
}

// ---------------- GEMM2 with in-staging scan fixup: relu(m Wfc^T + b) ----------------
// Same ring skeleton; B (weights) keeps the DMA path. A is reg-staged from
// m_local with the cross-segment fixup applied in flight:
//   m = m_local + bpow[t_loc+1][h] * F[seg][b][h]
// then bf16-packed and ds_write_b128 to the IDENTICAL linear LDS layout the
// DMA produced (thread tid -> u16 offsets tid*8 and 4096+tid*8), so the frag
// reads and swizzle are untouched. Loads for K-tile kt+3 are issued at iter
// kt (1-iteration lead); the write of slot kt+2 at iter kt is guarded by a
// conservative vmcnt(2): forces all but the 2 newest VMEM ops complete --
// correct under any legal reordering within the clobber-bounded region.
// Ring-slot reuse: writes to slot kt+2 are >=1 end-barrier after that slot's
// last ds_read (tenant kt-2), same argument as the DMA ring.
__global__ __launch_bounds__(512, 2) void gemm_fix(const u16* __restrict__ A,
                                                   const u16* __restrict__ B,
                                                   const float* __restrict__ bias,
                                                   float* __restrict__ Cout,
                                                   const float* __restrict__ bpow,
                                                   const float* __restrict__ Fbuf,
                                                   int M, int N, int K) {
  __shared__ u16 lds[4][2][256 * 32];  // 128 KiB ring

  const int tid  = threadIdx.x;
  const int lane = tid & 63;
  const int wid  = tid >> 6;
  const int wr   = (wid >> 2) * 128;
  const int wc   = (wid & 3) * 64;

  const int bid    = blockIdx.x;
  const int xcd    = bid & 7;
  const int idx    = bid >> 3;
  const int tile_m = ((xcd << 3) | (idx >> 2)) * 256;
  const int tile_n = (idx & 3) * 256;

  const int srow    = tid >> 2;                    // 0..127
  const int schunk  = (tid & 3) ^ ((srow >> 1) & 3);
  const int t0      = srow >> 3;                   // local t of row0 (0..15)
  const int bb      = srow & 7;                    // batch index of both rows
  const int seg     = tile_m >> 8;

  const u16*   gA2 = A + (size_t)(tile_m + srow) * K + schunk * 8;
  const u16*   gB  = B + (size_t)(tile_n + srow) * K + schunk * 8;
  const float* pb0 = bpow + (size_t)(t0 + 1) * 1024 + schunk * 8;
  const float* fb0 = Fbuf + (size_t)seg * 8192 + bb * 1024 + schunk * 8;
  const size_t half_stride = (size_t)128 * K;

  struct ARegs { uint4 m0, m1; float4 p0l, p0h, p1l, p1h, fl, fh; };
  ARegs rA, rB;

#define STAGE_B2(slot, kt)                                                \
  do {                                                                    \
    const size_t k0 = (size_t)(kt) * 32;                                  \
    async_load16(gB + k0,               &lds[slot][1][wid * 512]);        \
    async_load16(gB + k0 + half_stride, &lds[slot][1][4096 + wid * 512]); \
  } while (0)

#define LOADA(R, kt)                                                      \
  do {                                                                    \
    const size_t o = (size_t)(kt) * 32;                                   \
    (R).m0  = *(const uint4*)(gA2 + o);                                   \
    (R).m1  = *(const uint4*)(gA2 + o + half_stride);                     \
    (R).p0l = *(const float4*)(pb0 + o);                                  \
    (R).p0h = *(const float4*)(pb0 + o + 4);                              \
    (R).p1l = *(const float4*)(pb0 + o + 16384);                          \
    (R).p1h = *(const float4*)(pb0 + o + 16388);                          \
    (R).fl  = *(const float4*)(fb0 + o);                                  \
    (R).fh  = *(const float4*)(fb0 + o + 4);                              \
  } while (0)

#define FIXWRITE(slot, R)                                                 \
  do {                                                                    \
    uint4 w0, w1;                                                         \
    w0.x = fixpair((R).m0.x, (R).p0l.x, (R).p0l.y, (R).fl.x, (R).fl.y);   \
    w0.y = fixpair((R).m0.y, (R).p0l.z, (R).p0l.w, (R).fl.z, (R).fl.w);   \
    w0.z = fixpair((R).m0.z, (R).p0h.x, (R).p0h.y, (R).fh.x, (R).fh.y);   \
    w0.w = fixpair((R).m0.w, (R).p0h.z, (R).p0h.w, (R).fh.z, (R).fh.w);   \
    w1.x = fixpair((R).m1.x, (R).p1l.x, (R).p1l.y, (R).fl.x, (R).fl.y);   \
    w1.y = fixpair((R).m1.y, (R).p1l.z, (R).p1l.w, (R).fl.z, (R).fl.w);   \
    w1.z = fixpair((R).m1.z, (R).p1h.x, (R).p1h.y, (R).fh.x, (R).fh.y);   \
    w1.w = fixpair((R).m1.w, (R).p1h.z, (R).p1h.w, (R).fh.z, (R).fh.w);   \
    *(uint4*)&lds[slot][0][tid * 8]        = w0;                          \
    *(uint4*)&lds[slot][0][4096 + tid * 8] = w1;                          \
  } while (0)

  f32x4 acc[8][4];
#pragma unroll
  for (int i = 0; i < 8; i++)
#pragma unroll
    for (int j = 0; j < 4; j++) acc[i][j] = (f32x4){0.f, 0.f, 0.f, 0.f};

  const int lrow = lane & 15;
  const int kq   = lane >> 4;
  const int kc   = (lrow >> 1) & 3;
  const int coff = ((kq ^ kc) << 3);

  const int NKT = K >> 5;  // 32 (even)

  // ---- prologue: slots 0,1 built from regs; B 0..2 DMA'd; one-time full drain ----
  LOADA(rA, 0);
  LOADA(rB, 1);
  STAGE_B2(0, 0);
  STAGE_B2(1, 1);
  STAGE_B2(2, 2);
  asm volatile("s_waitcnt vmcnt(0)" ::: "memory");
  FIXWRITE(0, rA);
  FIXWRITE(1, rB);
  LOADA(rA, 2);  // rW for kt=0
  asm volatile("s_waitcnt lgkmcnt(0)" ::: "memory");
  __builtin_amdgcn_sched_barrier(0);
  __builtin_amdgcn_s_barrier();

#define ITER(kt, RW, RL)                                                      \
  do {                                                                       \
    const int slot = (kt) & 3;                                               \
    bf16x8 a[8], b[4];                                                       \
    _Pragma("unroll")                                                        \
    for (int i = 0; i < 8; i++)                                              \
      a[i] = *(const bf16x8*)&lds[slot][0][(wr + i * 16 + lrow) * 32 + coff];\
    _Pragma("unroll")                                                        \
    for (int j = 0; j < 4; j++)                                              \
      b[j] = *(const bf16x8*)&lds[slot][1][(wc + j * 16 + lrow) * 32 + coff];\
    if ((kt) + 3 < NKT) STAGE_B2(((kt) + 3) & 3, (kt) + 3);                  \
    if ((kt) + 2 < NKT) {                                                    \
      if ((kt) + 3 < NKT) asm volatile("s_waitcnt vmcnt(2)" ::: "memory");   \
      else                asm volatile("s_waitcnt vmcnt(0)" ::: "memory");   \
      FIXWRITE(((kt) + 2) & 3, RW);                                          \
    }                                                                        \
    if ((kt) + 3 < NKT) LOADA(RL, (kt) + 3);                                 \
    __builtin_amdgcn_s_setprio(1);                                           \
    _Pragma("unroll")                                                        \
    for (int i = 0; i < 8; i++)                                              \
      _Pragma("unroll")                                                      \
      for (int j = 0; j < 4; j++)                                            \
        acc[i][j] = __builtin_amdgcn_mfma_f32_16x16x32_bf16(a[i], b[j],      \
                                                            acc[i][j], 0, 0, 0); \
    __builtin_amdgcn_s_setprio(0);                                           \
    if ((kt) < NKT - 1) {                                                    \
      asm volatile("s_waitcnt lgkmcnt(0)" ::: "memory");                     \
      __builtin_amdgcn_sched_barrier(0);                                     \
      __builtin_amdgcn_s_barrier();                                          \
    }                                                                        \
  } while (0)

  for (int kt = 0; kt < NKT; kt += 2) {
    ITER(kt, rA, rB);
    ITER(kt + 1, rB, rA);
  }
#undef ITER
#undef FIXWRITE
#undef LOADA
#undef STAGE_B2

  // epilogue: bias + relu, fp32 out
  const int crow = (lane >> 4) << 2;
  const int ccol = lane & 15;
#pragma unroll
  for (int i = 0; i < 8; i++) {
#pragma unroll
    for (int j = 0; j < 4; j++) {
      const int gm = tile_m + wr + i * 16 + crow;
      const int gn = tile_n + wc + j * 16 + ccol;
      const float bv = bias[gn];
#pragma unroll
      for (int r = 0; r < 4; r++) {
        float v = acc[i][j][r] + bv;
        v = fmaxf(v, 0.f);
        Cout[(size_t)(gm + r) * N + gn] = v;
      }
    }
  }
}

extern "C" void kernel_launch(void* const* d_in, const int* in_sizes, int n_in,
                              void* d_out, int out_size, void* d_ws, size_t ws_size,
                              hipStream_t stream) {
  const float* x        = (const float*)d_in[0];
  const float* W_q      = (const float*)d_in[1];
  const float* b_q      = (const float*)d_in[2];
  const float* beta_raw = (const float*)d_in[3];
  const float* W_fc     = (const float*)d_in[4];
  const float* b_fc     = (const float*)d_in[5];

  const int H = 1024;
  const int M = 2048 * 8;              // T*B = 16384 rows
  const size_t MH = (size_t)M * H;     // 16.7M elements

  char* ws = (char*)d_ws;
  u16* x_bf    = (u16*)ws;  ws += MH * 2;                   // 32 MB
  u16* m_loc   = (u16*)ws;  ws += MH * 2;                   // 32 MB (m_bf round-trip is gone)
  u16* wq_bf   = (u16*)ws;  ws += (size_t)H * H * 2;        // 2 MB
  u16* wfc_bf  = (u16*)ws;  ws += (size_t)H * H * 2;        // 2 MB
  float* beta  = (float*)ws; ws += 4096;
  float* bpow  = (float*)ws; ws += 33 * 1024 * 4;           // 132 KB
  float* carry = (float*)ws; ws += (size_t)64 * 8192 * 4;   // 2 MB
  float* Fbuf  = (float*)ws; ws += (size_t)64 * 8192 * 4;   // 2 MB

  prep_all<<<(int)(MH / 8 / 256), 256, 0, stream>>>(x, W_q, W_fc, beta_raw,
                                                    x_bf, wq_bf, wfc_bf, beta, bpow);

  // GEMM1 + full in-register segment-local scan (writes m_local + carry)
  gemm_scan<<<256, 512, 0, stream>>>(x_bf, wq_bf, b_q, m_loc, beta, carry, M, H, H);

  // tiny: fold carries into per-segment prefixes F
  ffold<<<8, 256, 0, stream>>>((const float4*)carry, bpow, (float4*)Fbuf);

  // GEMM2 with cross-segment fixup fused into A-staging (m_bf round-trip eliminated)
  gemm_fix<<<256, 512, 0, stream>>>(m_loc, wfc_bf, b_fc, (float*)d_out,
                                    bpow, Fbuf, M, H, H);
}

// Round 7
// 237.635 us; speedup vs baseline: 1.4635x; 1.4635x over previous
//
#include <hip/hip_runtime.h>
#include <stdint.h>

typedef unsigned short u16;
typedef __bf16 bf16x8 __attribute__((ext_vector_type(8)));
typedef float f32x4 __attribute__((ext_vector_type(4)));

__device__ __forceinline__ u16 f2bf(float f) {
  union { float f; uint32_t u; } x; x.f = f;
  uint32_t u = x.u;
  u += 0x7fffu + ((u >> 16) & 1u);   // round-to-nearest-even
  return (u16)(u >> 16);
}
__device__ __forceinline__ float bf2f(uint32_t lo16) {
  union { uint32_t u; float f; } x; x.u = lo16 << 16; return x.f;
}
__device__ __forceinline__ float bfhi(uint32_t u) {
  union { uint32_t u; float f; } x; x.u = u & 0xffff0000u; return x.f;
}
// fix one bf16 pair: e_k = m_k + p_k * F_k, repacked to bf16x2
__device__ __forceinline__ uint32_t fixpair(uint32_t m, float p0, float p1,
                                            float F0, float F1) {
  float e0 = fmaf(p0, F0, bf2f(m & 0xffffu));
  float e1 = fmaf(p1, F1, bfhi(m));
  return (uint32_t)f2bf(e0) | ((uint32_t)f2bf(e1) << 16);
}

__device__ __forceinline__ void async_load16(const u16* g, u16* l) {
  __builtin_amdgcn_global_load_lds(
      (const __attribute__((address_space(1))) void*)g,
      (__attribute__((address_space(3))) void*)l,
      16, 0, 0);
}

// ---------------- prep_all: sigmoid(beta)+bpow table + weight/x converts ----------------
// bpow[p][h] = beta_h^p for p = 1..32 (fp32, 132 KB, L2-resident); bpow[32] is
// also ffold's beta^32 ratio.
__global__ __launch_bounds__(256) void prep_all(const float* __restrict__ x,
                                                const float* __restrict__ Wq,
                                                const float* __restrict__ Wfc,
                                                const float* __restrict__ braw,
                                                u16* __restrict__ xb,
                                                u16* __restrict__ wqb,
                                                u16* __restrict__ wfcb,
                                                float* __restrict__ beta,
                                                float* __restrict__ bpow) {
  int gid = blockIdx.x * 256 + threadIdx.x;
  if (gid < 1024) {
    float b = 1.0f / (1.0f + expf(-braw[gid]));
    beta[gid] = b;
    float w = b;
#pragma unroll 1
    for (int p = 1; p <= 32; p++) { bpow[p * 1024 + gid] = w; w *= b; }
  }
  if (gid < 131072) {
    const int HH = 1024 * 1024;
    int i = gid * 16;
    const float* src = (i < HH) ? (Wq + i) : (Wfc + (i - HH));
    u16* dst = (i < HH) ? (wqb + i) : (wfcb + (i - HH));
#pragma unroll
    for (int c = 0; c < 4; c++) {
      float4 v = *(const float4*)(src + c * 4);
      ushort4 o = {f2bf(v.x), f2bf(v.y), f2bf(v.z), f2bf(v.w)};
      *(ushort4*)(dst + c * 4) = o;
    }
  }
  {
    int i = gid * 8;
    float4 a = *(const float4*)(x + i);
    float4 b = *(const float4*)(x + i + 4);
    ushort4 o0 = {f2bf(a.x), f2bf(a.y), f2bf(a.z), f2bf(a.w)};
    ushort4 o1 = {f2bf(b.x), f2bf(b.y), f2bf(b.z), f2bf(b.w)};
    *(ushort4*)(xb + i) = o0;
    *(ushort4*)(xb + i + 4) = o1;
  }
}

// ---------------- GEMM1 + fused segment-local scan: m_local = localscan(x Wq^T + b) ----
// Ring schedule = R1/R4 harness-verified (256x256 tile, BK=32, 4-deep LDS ring,
// counted vmcnt(8), XCD swizzle). Epilogue computes the FULL segment-local scan
// in-register (one block = one 32t x 8b segment) and writes bf16 m_local + the
// segment carry m(31). fp32 q feeds the scan.
__global__ __launch_bounds__(512, 2) void gemm_scan(const u16* __restrict__ A,
                                                    const u16* __restrict__ B,
                                                    const float* __restrict__ bias,
                                                    u16* __restrict__ Cout,
                                                    const float* __restrict__ beta_arr,
                                                    float* __restrict__ carry_out,
                                                    int M, int N, int K) {
  __shared__ u16 lds[4][2][256 * 32];  // 128 KiB ring

  const int tid  = threadIdx.x;
  const int lane = tid & 63;
  const int wid  = tid >> 6;
  const int wr   = (wid >> 2) * 128;
  const int wc   = (wid & 3) * 64;

  const int bid    = blockIdx.x;
  const int xcd    = bid & 7;
  const int idx    = bid >> 3;
  const int tile_m = ((xcd << 3) | (idx >> 2)) * 256;
  const int tile_n = (idx & 3) * 256;

  const int srow    = tid >> 2;
  const int schunk  = (tid & 3) ^ ((srow >> 1) & 3);
  const u16* gA = A + (size_t)(tile_m + srow) * K + schunk * 8;
  const u16* gB = B + (size_t)(tile_n + srow) * K + schunk * 8;
  const size_t half_stride = (size_t)128 * K;

#define STAGE(slot, kt)                                                   \
  do {                                                                    \
    const size_t k0 = (size_t)(kt) * 32;                                  \
    async_load16(gA + k0,               &lds[slot][0][wid * 512]);        \
    async_load16(gA + k0 + half_stride, &lds[slot][0][4096 + wid * 512]); \
    async_load16(gB + k0,               &lds[slot][1][wid * 512]);        \
    async_load16(gB + k0 + half_stride, &lds[slot][1][4096 + wid * 512]); \
  } while (0)

  f32x4 acc[8][4];
#pragma unroll
  for (int i = 0; i < 8; i++)
#pragma unroll
    for (int j = 0; j < 4; j++) acc[i][j] = (f32x4){0.f, 0.f, 0.f, 0.f};

  const int lrow = lane & 15;
  const int kq   = lane >> 4;
  const int kc   = (lrow >> 1) & 3;
  const int coff = ((kq ^ kc) << 3);

  const int NKT = K >> 5;  // 32

  STAGE(0, 0);
  if (NKT > 1) STAGE(1, 1);
  if (NKT > 2) STAGE(2, 2);
  if (NKT > 2)      asm volatile("s_waitcnt vmcnt(8)" ::: "memory");
  else if (NKT > 1) asm volatile("s_waitcnt vmcnt(4)" ::: "memory");
  else              asm volatile("s_waitcnt vmcnt(0)" ::: "memory");
  __builtin_amdgcn_s_barrier();

  for (int kt = 0; kt < NKT; ++kt) {
    const int slot = kt & 3;
    const u16* As = &lds[slot][0][0];
    const u16* Bs = &lds[slot][1][0];

    bf16x8 a[8], b[4];
#pragma unroll
    for (int i = 0; i < 8; i++)
      a[i] = *(const bf16x8*)&As[(wr + i * 16 + lrow) * 32 + coff];
#pragma unroll
    for (int j = 0; j < 4; j++)
      b[j] = *(const bf16x8*)&Bs[(wc + j * 16 + lrow) * 32 + coff];

    if (kt + 3 < NKT) STAGE((kt + 3) & 3, kt + 3);

    __builtin_amdgcn_s_setprio(1);
#pragma unroll
    for (int i = 0; i < 8; i++)
#pragma unroll
      for (int j = 0; j < 4; j++)
        acc[i][j] = __builtin_amdgcn_mfma_f32_16x16x32_bf16(a[i], b[j], acc[i][j], 0, 0, 0);
    __builtin_amdgcn_s_setprio(0);

    const int ahead = NKT - 1 - kt;
    if (ahead >= 3) {
      asm volatile("s_waitcnt vmcnt(8)" ::: "memory");
      __builtin_amdgcn_s_barrier();
    } else if (ahead == 2) {
      asm volatile("s_waitcnt vmcnt(4)" ::: "memory");
      __builtin_amdgcn_s_barrier();
    } else if (ahead == 1) {
      asm volatile("s_waitcnt vmcnt(0)" ::: "memory");
      __builtin_amdgcn_s_barrier();
    }
  }
#undef STAGE

  // ---------------- fused segment-local scan epilogue ----------------
  const int crow = (lane >> 4) << 2;
  const int ccol = lane & 15;
  const int c4   = lane >> 4;
  const int kap  = c4 >> 1;
  const int Wh   = wr >> 7;
  float* sm15 = (float*)&lds[0][0][0];  // [8][256] fp32, 8 KB (ring slot 0)

  // Phase A: local (t-half) scan, in place in acc
#pragma unroll
  for (int j = 0; j < 4; j++) {
    const int gn = tile_n + wc + j * 16 + ccol;
    const float bv = bias[gn];
    const float be = beta_arr[gn];
    const float be2 = be * be;
#pragma unroll
    for (int r = 0; r < 4; r++) {
      float S[8], R[8];
      S[0] = acc[0][j][r] + bv;
#pragma unroll
      for (int i = 1; i < 8; i++) S[i] = fmaf(be2, S[i - 1], acc[i][j][r] + bv);
#pragma unroll
      for (int i = 0; i < 8; i++) R[i] = __shfl_xor(S[i], 32);
      acc[0][j][r] = kap ? fmaf(be, R[0], S[0]) : S[0];
#pragma unroll
      for (int i = 1; i < 8; i++)
        acc[i][j][r] = fmaf(be, kap ? R[i] : R[i - 1], S[i]);
    }
  }
  // Phase B: export m(15)
  if (Wh == 0 && kap == 1) {
#pragma unroll
    for (int j = 0; j < 4; j++)
#pragma unroll
      for (int r = 0; r < 4; r++) {
        const int bb = ((c4 << 2) + r) & 7;
        sm15[bb * 256 + wc + j * 16 + ccol] = acc[7][j][r];
      }
  }
  __syncthreads();
  // Phase C: upper half adds beta^{2i+kap+1} * m(15)
  if (Wh == 1) {
#pragma unroll
    for (int j = 0; j < 4; j++) {
      const int hl = wc + j * 16 + ccol;
      const float be = beta_arr[tile_n + hl];
      const float be2 = be * be;
#pragma unroll
      for (int r = 0; r < 4; r++) {
        const int bb = ((c4 << 2) + r) & 7;
        const float v = sm15[bb * 256 + hl];
        float f = kap ? be2 : be;
#pragma unroll
        for (int i = 0; i < 8; i++) {
          acc[i][j][r] = fmaf(f, v, acc[i][j][r]);
          f *= be2;
        }
      }
    }
  }
  // Phase D: store bf16 m_local (+ per-segment carry from registers)
#pragma unroll
  for (int i = 0; i < 8; i++) {
#pragma unroll
    for (int j = 0; j < 4; j++) {
      const int gm = tile_m + wr + i * 16 + crow;
      const int gn = tile_n + wc + j * 16 + ccol;
#pragma unroll
      for (int r = 0; r < 4; r++)
        Cout[(size_t)(gm + r) * N + gn] = f2bf(acc[i][j][r]);
    }
  }
  if (Wh == 1 && kap == 1) {
    const int seg = tile_m >> 8;
#pragma unroll
    for (int j = 0; j < 4; j++) {
      const int hl = wc + j * 16 + ccol;
#pragma unroll
      for (int r = 0; r < 4; r++) {
        const int bb = ((c4 << 2) + r) & 7;
        carry_out[(size_t)seg * 8192 + bb * 1024 + tile_n + hl] = acc[7][j][r];
      }
    }
  }
}

// ---------------- ffold: F[s] = beta^32 * F[s-1] + carry[s-1], F[0] = 0 ----------------
// b32 indexed by h = (cq*4)&1023 (per-h table; R5's cq*4 indexing overran it).
__global__ __launch_bounds__(256) void ffold(const float4* __restrict__ carry4,
                                             const float* __restrict__ bpow,
                                             float4* __restrict__ Fbuf) {
  const int cq = blockIdx.x * 256 + threadIdx.x;  // 0..2047  (= b*256 + h/4)
  const int hq = cq & 255;                        // h quad: h = hq*4 .. hq*4+3
  const float4 b32 = *(const float4*)&bpow[32 * 1024 + hq * 4];
  float4 F = make_float4(0.f, 0.f, 0.f, 0.f);
  for (int s = 0; s < 64; s++) {
    Fbuf[(size_t)s * 2048 + cq] = F;
    float4 c = carry4[(size_t)s * 2048 + cq];
    F.x = fmaf(b32.x, F.x, c.x);
    F.y = fmaf(b32.y, F.y, c.y);
    F.z = fmaf(b32.z, F.z, c.z);
    F.w = fmaf(b32.w, F.w, c.w);
  }
}

// ---------------- GEMM2 with in-staging scan fixup: relu(m Wfc^T + b) ----------------
// R7 spill fix: (a) __launch_bounds__(512, 1) -- the old (512,2) capped VGPRs
// at 128 for a 2-blocks/CU promise that 128 KiB LDS makes impossible anyway
// (1 block/CU either way; grid = 256 = 1/CU), so everything past 128 regs
// spilled to scratch (R6: WRITE_SIZE 549 MB, MfmaUtil 7%). (b) SINGLE ARegs
// staging buffer: R is loaded at iter kt (data for tile kt+3), consumed by
// FIXWRITE at iter kt+1, then immediately reloaded -- register deps are
// compiler-tracked, no runtime indexing (rule 20), peak live state ~halved.
//
// Pipeline per iter kt (VMEM issue order fixed by sched_barrier(0) fences):
//   ds_read frags(slot kt) | STAGE_B2(kt+3) [2 DMA] |
//   vmcnt(2) -> forces LOADA(kt+2)'s 8 loads (issued last iter) + all older
//   B-DMA done; only this iter's 2 DMA may fly | FIXWRITE(kt+2) |
//   LOADA(R, kt+3) [8 loads] | MFMA x32 | lgkmcnt(0); barrier.
// Tail: vmcnt(0) when no newer DMA exists. Ring-slot overwrite safety is the
// R1 ring argument (write at kt+2 >= 1 collective barrier after that slot's
// last reads at kt-2).
__global__ __launch_bounds__(512, 1) void gemm_fix(const u16* __restrict__ A,
                                                   const u16* __restrict__ B,
                                                   const float* __restrict__ bias,
                                                   float* __restrict__ Cout,
                                                   const float* __restrict__ bpow,
                                                   const float* __restrict__ Fbuf,
                                                   int M, int N, int K) {
  __shared__ u16 lds[4][2][256 * 32];  // 128 KiB ring

  const int tid  = threadIdx.x;
  const int lane = tid & 63;
  const int wid  = tid >> 6;
  const int wr   = (wid >> 2) * 128;
  const int wc   = (wid & 3) * 64;

  const int bid    = blockIdx.x;
  const int xcd    = bid & 7;
  const int idx    = bid >> 3;
  const int tile_m = ((xcd << 3) | (idx >> 2)) * 256;
  const int tile_n = (idx & 3) * 256;

  const int srow    = tid >> 2;                    // 0..127
  const int schunk  = (tid & 3) ^ ((srow >> 1) & 3);
  const int t0      = srow >> 3;                   // local t of row0 (0..15)
  const int bb      = srow & 7;                    // batch index of both rows
  const int seg     = tile_m >> 8;

  const u16*   gA2 = A + (size_t)(tile_m + srow) * K + schunk * 8;
  const u16*   gB  = B + (size_t)(tile_n + srow) * K + schunk * 8;
  const float* pb0 = bpow + (size_t)(t0 + 1) * 1024 + schunk * 8;
  const float* fb0 = Fbuf + (size_t)seg * 8192 + bb * 1024 + schunk * 8;
  const size_t half_stride = (size_t)128 * K;

  struct ARegs { uint4 m0, m1; float4 p0l, p0h, p1l, p1h, fl, fh; };
  ARegs R;  // single staging set (32 VGPRs)

#define STAGE_B2(slot, kt)                                                \
  do {                                                                    \
    const size_t k0 = (size_t)(kt) * 32;                                  \
    async_load16(gB + k0,               &lds[slot][1][wid * 512]);        \
    async_load16(gB + k0 + half_stride, &lds[slot][1][4096 + wid * 512]); \
  } while (0)

#define LOADA(kt)                                                         \
  do {                                                                    \
    const size_t o = (size_t)(kt) * 32;                                   \
    R.m0  = *(const uint4*)(gA2 + o);                                     \
    R.m1  = *(const uint4*)(gA2 + o + half_stride);                       \
    R.p0l = *(const float4*)(pb0 + o);                                    \
    R.p0h = *(const float4*)(pb0 + o + 4);                                \
    R.p1l = *(const float4*)(pb0 + o + 16384);                            \
    R.p1h = *(const float4*)(pb0 + o + 16388);                            \
    R.fl  = *(const float4*)(fb0 + o);                                    \
    R.fh  = *(const float4*)(fb0 + o + 4);                                \
  } while (0)

#define FIXWRITE(slot)                                                    \
  do {                                                                    \
    uint4 w0, w1;                                                         \
    w0.x = fixpair(R.m0.x, R.p0l.x, R.p0l.y, R.fl.x, R.fl.y);             \
    w0.y = fixpair(R.m0.y, R.p0l.z, R.p0l.w, R.fl.z, R.fl.w);             \
    w0.z = fixpair(R.m0.z, R.p0h.x, R.p0h.y, R.fh.x, R.fh.y);             \
    w0.w = fixpair(R.m0.w, R.p0h.z, R.p0h.w, R.fh.z, R.fh.w);             \
    w1.x = fixpair(R.m1.x, R.p1l.x, R.p1l.y, R.fl.x, R.fl.y);             \
    w1.y = fixpair(R.m1.y, R.p1l.z, R.p1l.w, R.fl.z, R.fl.w);             \
    w1.z = fixpair(R.m1.z, R.p1h.x, R.p1h.y, R.fh.x, R.fh.y);             \
    w1.w = fixpair(R.m1.w, R.p1h.z, R.p1h.w, R.fh.z, R.fh.w);             \
    *(uint4*)&lds[slot][0][tid * 8]        = w0;                          \
    *(uint4*)&lds[slot][0][4096 + tid * 8] = w1;                          \
  } while (0)

  f32x4 acc[8][4];
#pragma unroll
  for (int i = 0; i < 8; i++)
#pragma unroll
    for (int j = 0; j < 4; j++) acc[i][j] = (f32x4){0.f, 0.f, 0.f, 0.f};

  const int lrow = lane & 15;
  const int kq   = lane >> 4;
  const int kc   = (lrow >> 1) & 3;
  const int coff = ((kq ^ kc) << 3);

  const int NKT = K >> 5;  // 32

  // ---- prologue: B 0..2 DMA'd; slots 0,1 A built via single R; R <- A(2) ----
  STAGE_B2(0, 0);
  STAGE_B2(1, 1);
  STAGE_B2(2, 2);
  LOADA(0);
  asm volatile("s_waitcnt vmcnt(0)" ::: "memory");
  FIXWRITE(0);
  LOADA(1);
  asm volatile("s_waitcnt vmcnt(0)" ::: "memory");
  FIXWRITE(1);
  LOADA(2);  // consumed at iter 0 (guarded by its vmcnt(2))
  asm volatile("s_waitcnt lgkmcnt(0)" ::: "memory");
  __builtin_amdgcn_sched_barrier(0);
  __builtin_amdgcn_s_barrier();

  for (int kt = 0; kt < NKT; ++kt) {
    const int slot = kt & 3;
    bf16x8 a[8], b[4];
#pragma unroll
    for (int i = 0; i < 8; i++)
      a[i] = *(const bf16x8*)&lds[slot][0][(wr + i * 16 + lrow) * 32 + coff];
#pragma unroll
    for (int j = 0; j < 4; j++)
      b[j] = *(const bf16x8*)&lds[slot][1][(wc + j * 16 + lrow) * 32 + coff];

    if (kt + 3 < NKT) STAGE_B2((kt + 3) & 3, kt + 3);
    __builtin_amdgcn_sched_barrier(0);
    if (kt + 2 < NKT) {
      if (kt + 3 < NKT) asm volatile("s_waitcnt vmcnt(2)" ::: "memory");
      else              asm volatile("s_waitcnt vmcnt(0)" ::: "memory");
      FIXWRITE((kt + 2) & 3);
    }
    if (kt + 3 < NKT) LOADA(kt + 3);
    __builtin_amdgcn_sched_barrier(0);

    __builtin_amdgcn_s_setprio(1);
#pragma unroll
    for (int i = 0; i < 8; i++)
#pragma unroll
      for (int j = 0; j < 4; j++)
        acc[i][j] = __builtin_amdgcn_mfma_f32_16x16x32_bf16(a[i], b[j], acc[i][j], 0, 0, 0);
    __builtin_amdgcn_s_setprio(0);

    if (kt < NKT - 1) {
      asm volatile("s_waitcnt lgkmcnt(0)" ::: "memory");
      __builtin_amdgcn_sched_barrier(0);
      __builtin_amdgcn_s_barrier();
    }
  }
#undef FIXWRITE
#undef LOADA
#undef STAGE_B2

  // epilogue: bias + relu, fp32 out
  const int crow = (lane >> 4) << 2;
  const int ccol = lane & 15;
#pragma unroll
  for (int i = 0; i < 8; i++) {
#pragma unroll
    for (int j = 0; j < 4; j++) {
      const int gm = tile_m + wr + i * 16 + crow;
      const int gn = tile_n + wc + j * 16 + ccol;
      const float bv = bias[gn];
#pragma unroll
      for (int r = 0; r < 4; r++) {
        float v = acc[i][j][r] + bv;
        v = fmaxf(v, 0.f);
        Cout[(size_t)(gm + r) * N + gn] = v;
      }
    }
  }
}

extern "C" void kernel_launch(void* const* d_in, const int* in_sizes, int n_in,
                              void* d_out, int out_size, void* d_ws, size_t ws_size,
                              hipStream_t stream) {
  const float* x        = (const float*)d_in[0];
  const float* W_q      = (const float*)d_in[1];
  const float* b_q      = (const float*)d_in[2];
  const float* beta_raw = (const float*)d_in[3];
  const float* W_fc     = (const float*)d_in[4];
  const float* b_fc     = (const float*)d_in[5];

  const int H = 1024;
  const int M = 2048 * 8;              // T*B = 16384 rows
  const size_t MH = (size_t)M * H;     // 16.7M elements

  char* ws = (char*)d_ws;
  u16* x_bf    = (u16*)ws;  ws += MH * 2;                   // 32 MB
  u16* m_loc   = (u16*)ws;  ws += MH * 2;                   // 32 MB
  u16* wq_bf   = (u16*)ws;  ws += (size_t)H * H * 2;        // 2 MB
  u16* wfc_bf  = (u16*)ws;  ws += (size_t)H * H * 2;        // 2 MB
  float* beta  = (float*)ws; ws += 4096;
  float* bpow  = (float*)ws; ws += 33 * 1024 * 4;           // 132 KB
  float* carry = (float*)ws; ws += (size_t)64 * 8192 * 4;   // 2 MB
  float* Fbuf  = (float*)ws; ws += (size_t)64 * 8192 * 4;   // 2 MB

  prep_all<<<(int)(MH / 8 / 256), 256, 0, stream>>>(x, W_q, W_fc, beta_raw,
                                                    x_bf, wq_bf, wfc_bf, beta, bpow);

  // GEMM1 + full in-register segment-local scan (writes m_local + carry)
  gemm_scan<<<256, 512, 0, stream>>>(x_bf, wq_bf, b_q, m_loc, beta, carry, M, H, H);

  // tiny: fold carries into per-segment prefixes F
  ffold<<<8, 256, 0, stream>>>((const float4*)carry, bpow, (float4*)Fbuf);

  // GEMM2 with cross-segment fixup fused into A-staging
  gemm_fix<<<256, 512, 0, stream>>>(m_loc, wfc_bf, b_fc, (float*)d_out,
                                    bpow, Fbuf, M, H, H);
}